// Round 18
// baseline (206.075 us; speedup 1.0000x reference)
//
#include <hip/hip_runtime.h>
#include <hip/hip_bf16.h>
#include <stdint.h>

// Problem dims (fixed by the reference)
#define B_DIM   8192
#define LAT     256
#define MEM_DIM 200
#define MEM_PAD 208            // padded to 13 x 16-row MFMA fragments (phase-1 B-operand)
#define MEMT_K  224            // memT k-dim padded to 7 x 32 (phase-3 contraction)
#define MEMT_S  232            // memT row stride (bf16)
#define NPIX    16384          // IMG*IMG = 128*128
#define RPB     16             // batch rows per block (r15-proven efficient)
#define W_QUADS (NPIX * LAT / 4)    // 1,048,576
#define Z_QUADS (B_DIM * LAT / 4)   //   524,288

typedef short bf16x8 __attribute__((ext_vector_type(8)));
typedef float f32x4  __attribute__((ext_vector_type(4)));

__device__ __forceinline__ float wred_sum(float v) {
#pragma unroll
  for (int m = 32; m; m >>= 1) v += __shfl_xor(v, m, 64);
  return v;
}
__device__ __forceinline__ float wred_max(float v) {
#pragma unroll
  for (int m = 32; m; m >>= 1) v = fmaxf(v, __shfl_xor(v, m, 64));
  return v;
}
// round-to-nearest-even fp32 -> bf16 (bit trick; inputs are normal floats)
__device__ __forceinline__ unsigned short f2bf(float f) {
  unsigned u = __builtin_bit_cast(unsigned, f);
  u = u + 0x7FFFu + ((u >> 16) & 1u);
  return (unsigned short)(u >> 16);
}
__device__ __forceinline__ float bf2f(unsigned short h) {
  return __builtin_bit_cast(float, (unsigned)h << 16);
}
// 3-level bf16 split: v = h + m + l + r, |r| <= 2^-27 |v|
__device__ __forceinline__ void split3(float v, unsigned short& h, unsigned short& m,
                                       unsigned short& l) {
  h = f2bf(v);
  float r1 = v - bf2f(h);
  m = f2bf(r1);
  float r2 = r1 - bf2f(m);
  l = f2bf(r2);
}

// ------- memory prep: row norms + 3-way split (rows) + 3-way split TRANSPOSE -------
__global__ void __launch_bounds__(64) mem_norm_kernel(
    const float* __restrict__ mem, float* __restrict__ mn,
    unsigned short* __restrict__ mem_h, unsigned short* __restrict__ mem_m,
    unsigned short* __restrict__ mem_l,
    unsigned short* __restrict__ memT_h, unsigned short* __restrict__ memT_m,
    unsigned short* __restrict__ memT_l) {
  const int m = blockIdx.x, lane = threadIdx.x;
  if (m >= MEM_DIM) {
    ushort4 zz = {0, 0, 0, 0};
    if (m < MEM_PAD) {
      ((ushort4*)(mem_h + (size_t)m * LAT))[lane] = zz;
      ((ushort4*)(mem_m + (size_t)m * LAT))[lane] = zz;
      ((ushort4*)(mem_l + (size_t)m * LAT))[lane] = zz;
    }
#pragma unroll
    for (int q = 0; q < 4; ++q) {
      const size_t o = (size_t)(lane * 4 + q) * MEMT_S + m;
      memT_h[o] = 0; memT_m[o] = 0; memT_l[o] = 0;
    }
    return;
  }
  float4 v = ((const float4*)(mem + (size_t)m * LAT))[lane];
  ushort4 h, md, l;
  split3(v.x, h.x, md.x, l.x); split3(v.y, h.y, md.y, l.y);
  split3(v.z, h.z, md.z, l.z); split3(v.w, h.w, md.w, l.w);
  ((ushort4*)(mem_h + (size_t)m * LAT))[lane] = h;
  ((ushort4*)(mem_m + (size_t)m * LAT))[lane] = md;
  ((ushort4*)(mem_l + (size_t)m * LAT))[lane] = l;
  const float vv[4] = {v.x, v.y, v.z, v.w};
#pragma unroll
  for (int q = 0; q < 4; ++q) {
    unsigned short th, tm, tl;
    split3(vv[q], th, tm, tl);
    const size_t o = (size_t)(lane * 4 + q) * MEMT_S + m;
    memT_h[o] = th; memT_m[o] = tm; memT_l[o] = tl;
  }
  float ss = v.x * v.x + v.y * v.y + v.z * v.z + v.w * v.w;
  ss = wred_sum(ss);
  if (lane == 0) mn[m] = sqrtf(ss);
}

// ------- fused prep: W fp32->bf16 convert + z 3-way split (one launch) -------
__global__ void __launch_bounds__(256) prep_kernel(
    const float* __restrict__ W, unsigned short* __restrict__ Wb,
    const float* __restrict__ z, unsigned short* __restrict__ z_h,
    unsigned short* __restrict__ z_m, unsigned short* __restrict__ z_l) {
  const int i = blockIdx.x * 256 + threadIdx.x;
  if (i < W_QUADS) {
    float4 v = ((const float4*)W)[i];
    ushort4 o;
    o.x = f2bf(v.x); o.y = f2bf(v.y); o.z = f2bf(v.z); o.w = f2bf(v.w);
    ((ushort4*)Wb)[i] = o;
  } else {
    const int j = i - W_QUADS;
    float4 v = ((const float4*)z)[j];
    ushort4 h, md, l;
    split3(v.x, h.x, md.x, l.x); split3(v.y, h.y, md.y, l.y);
    split3(v.z, h.z, md.z, l.z); split3(v.w, h.w, md.w, l.w);
    ((ushort4*)z_h)[j] = h;
    ((ushort4*)z_m)[j] = md;
    ((ushort4*)z_l)[j] = l;
  }
}

// ---------------- fused per-row pipeline ----------------
// Round-18: 512 threads / 8 waves per block, SAME RPB=16 (no padding waste --
// r16's lesson). Row work per wave halves everywhere: phase 1 splits 13 frags
// 8 ways, phase 2 gives each wave 2 rows (identical per-row math -> bitwise-
// same w/zhat), phase 3 splits d 8 ways. Occupancy 8 -> 16 waves/CU (2 blocks
// x 8 waves; LDS 35.4KB). Attacks the measured 2-waves/SIMD latency exposure.
__global__ void __launch_bounds__(512, 4) row_kernel(
    const float* __restrict__ z, const float* __restrict__ mn_g,
    const unsigned short* __restrict__ z_h, const unsigned short* __restrict__ z_m,
    const unsigned short* __restrict__ z_l,
    const unsigned short* __restrict__ mem_h, const unsigned short* __restrict__ mem_m,
    const unsigned short* __restrict__ mem_l,
    const unsigned short* __restrict__ memT_h, const unsigned short* __restrict__ memT_m,
    const unsigned short* __restrict__ memT_l,
    float* __restrict__ zhat_out, float* __restrict__ w_out,
    unsigned short* __restrict__ zhat_bf) {
  __shared__ float lw[RPB][MEM_DIM];              // 12.8 KB: logits, then final w
  __shared__ float mnsh[MEM_DIM];
  __shared__ unsigned short whsh[16 * MEMT_S];    // 7.25 KB x3: w splits
  __shared__ unsigned short wmsh[16 * MEMT_S];
  __shared__ unsigned short wlsh[16 * MEMT_S];

  const int tid = threadIdx.x;
  const int lane = tid & 63;
  const int wid = tid >> 6;                        // 0..7
  const int row0 = blockIdx.x * RPB;
  const int fr_ = lane & 15;
  const int kq8 = (lane >> 4) * 8;

  if (tid < MEM_DIM) mnsh[tid] = mn_g[tid];

  // z norms: wave owns 2 rows (exact fp32, same per-row op order as always)
  float zn[2];
#pragma unroll
  for (int r = 0; r < 2; ++r) {
    const int row = row0 + wid * 2 + r;
    float4 zr = *(const float4*)(z + (size_t)row * LAT + lane * 4);
    float ss = zr.x * zr.x + zr.y * zr.y + zr.z * zr.z + zr.w * zr.w;
    zn[r] = sqrtf(wred_sum(ss));
  }

  // ---- phase 1: logits via 6-term split MFMA (13 frags over 8 waves) ----
  {
    const size_t zoff = (size_t)(row0 + fr_) * LAT + kq8;
    const unsigned short* zh_p = z_h + zoff;
    const unsigned short* zm_p = z_m + zoff;
    const unsigned short* zl_p = z_l + zoff;
    for (int nf = wid; nf <= 12; nf += 8) {
      const size_t moff = (size_t)(nf * 16 + fr_) * LAT + kq8;
      const unsigned short* mh_p = mem_h + moff;
      const unsigned short* mm_p = mem_m + moff;
      const unsigned short* ml_p = mem_l + moff;
      f32x4 a = {};
#pragma unroll
      for (int kk = 0; kk < 8; ++kk) {
        bf16x8 zh = *(const bf16x8*)(zh_p + kk * 32);
        bf16x8 zm = *(const bf16x8*)(zm_p + kk * 32);
        bf16x8 zl = *(const bf16x8*)(zl_p + kk * 32);
        bf16x8 mh = *(const bf16x8*)(mh_p + kk * 32);
        bf16x8 mm = *(const bf16x8*)(mm_p + kk * 32);
        bf16x8 ml = *(const bf16x8*)(ml_p + kk * 32);
        a = __builtin_amdgcn_mfma_f32_16x16x32_bf16(zm, mm, a, 0, 0, 0);
        a = __builtin_amdgcn_mfma_f32_16x16x32_bf16(zh, ml, a, 0, 0, 0);
        a = __builtin_amdgcn_mfma_f32_16x16x32_bf16(zl, mh, a, 0, 0, 0);
        a = __builtin_amdgcn_mfma_f32_16x16x32_bf16(zm, mh, a, 0, 0, 0);
        a = __builtin_amdgcn_mfma_f32_16x16x32_bf16(zh, mm, a, 0, 0, 0);
        a = __builtin_amdgcn_mfma_f32_16x16x32_bf16(zh, mh, a, 0, 0, 0);
      }
      const int m = nf * 16 + fr_;
      if (m < MEM_DIM) {
#pragma unroll
        for (int q = 0; q < 4; ++q)
          lw[(lane >> 4) * 4 + q][m] = a[q];
      }
    }
  }
  __syncthreads();

  // ---- phase 2: cosine scale -> softmax -> shrink -> L1 (2 rows/wave) ----
  const float t = 0.005f;
#pragma unroll
  for (int r = 0; r < 2; ++r) {
    const int lr = wid * 2 + r;
    float lg[4];
#pragma unroll
    for (int i = 0; i < 4; ++i) {
      const int m = lane + 64 * i;
      lg[i] = (m < MEM_DIM) ? lw[lr][m] / fmaxf(zn[r] * mnsh[m], 1e-8f) : -1e30f;
    }
    float mx = wred_max(fmaxf(fmaxf(lg[0], lg[1]), fmaxf(lg[2], lg[3])));
    float e[4]; float s = 0.f;
#pragma unroll
    for (int i = 0; i < 4; ++i) {
      const int m = lane + 64 * i;
      e[i] = (m < MEM_DIM) ? expf(lg[i] - mx) : 0.f;
      s += e[i];
    }
    s = wred_sum(s);
    float sv[4]; float l1 = 0.f;
#pragma unroll
    for (int i = 0; i < 4; ++i) {
      const float wv = e[i] / s;
      const float d = wv - t;
      sv[i] = fmaxf(d, 0.f) * wv / (fabsf(d) + 1e-12f);
      l1 += sv[i];
    }
    l1 = wred_sum(l1);
    const float dnm = fmaxf(l1, 1e-12f);
#pragma unroll
    for (int i = 0; i < 4; ++i) {
      const int m = lane + 64 * i;
      if (m < MEM_DIM) {
        const float wn = sv[i] / dnm;
        lw[lr][m] = wn;
        w_out[(size_t)(row0 + lr) * MEM_DIM + m] = wn;
      }
    }
  }
  __syncthreads();

  // ---- phase 2.5: split w -> bf16 h/m/l fragment arrays in LDS ----
  for (int idx = tid; idx < 16 * MEMT_S; idx += 512) {
    const int lr = idx / MEMT_S, m = idx % MEMT_S;
    const float val = (m < MEM_DIM) ? lw[lr][m] : 0.f;
    unsigned short h, md, l;
    split3(val, h, md, l);
    whsh[idx] = h; wmsh[idx] = md; wlsh[idx] = l;
  }
  __syncthreads();

  // ---- phase 3: z_hat = w @ mem via 6-term split MFMA (d split 8 ways) ----
  {
    f32x4 zacc[2] = {};
    for (int kk = 0; kk < 7; ++kk) {
      const int ko = kk * 32 + kq8;
      bf16x8 wh = *(const bf16x8*)&whsh[fr_ * MEMT_S + ko];
      bf16x8 wm = *(const bf16x8*)&wmsh[fr_ * MEMT_S + ko];
      bf16x8 wl = *(const bf16x8*)&wlsh[fr_ * MEMT_S + ko];
#pragma unroll
      for (int nf = 0; nf < 2; ++nf) {
        const size_t mo = (size_t)(wid * 32 + nf * 16 + fr_) * MEMT_S + ko;
        bf16x8 th = *(const bf16x8*)(memT_h + mo);
        bf16x8 tm = *(const bf16x8*)(memT_m + mo);
        bf16x8 tl = *(const bf16x8*)(memT_l + mo);
        zacc[nf] = __builtin_amdgcn_mfma_f32_16x16x32_bf16(tm, wm, zacc[nf], 0, 0, 0);
        zacc[nf] = __builtin_amdgcn_mfma_f32_16x16x32_bf16(th, wl, zacc[nf], 0, 0, 0);
        zacc[nf] = __builtin_amdgcn_mfma_f32_16x16x32_bf16(tl, wh, zacc[nf], 0, 0, 0);
        zacc[nf] = __builtin_amdgcn_mfma_f32_16x16x32_bf16(tm, wh, zacc[nf], 0, 0, 0);
        zacc[nf] = __builtin_amdgcn_mfma_f32_16x16x32_bf16(th, wm, zacc[nf], 0, 0, 0);
        zacc[nf] = __builtin_amdgcn_mfma_f32_16x16x32_bf16(th, wh, zacc[nf], 0, 0, 0);
      }
    }
    const size_t orow = (size_t)(row0 + fr_) * LAT;
#pragma unroll
    for (int nf = 0; nf < 2; ++nf) {
      const int d0 = wid * 32 + nf * 16 + (lane >> 4) * 4;
      float4 o;
      o.x = zacc[nf][0]; o.y = zacc[nf][1]; o.z = zacc[nf][2]; o.w = zacc[nf][3];
      *(float4*)(zhat_out + orow + d0) = o;
      ushort4 ob;
      ob.x = f2bf(o.x); ob.y = f2bf(o.y); ob.z = f2bf(o.z); ob.w = f2bf(o.w);
      *(ushort4*)(zhat_bf + orow + d0) = ob;
    }
  }
}

// ---------------- x_hat = zhat_bf @ Wb^T + bias (r17 version, UNCHANGED) ----------------
#define TSTRIDE 68
__global__ void __launch_bounds__(256, 4) gemm_xhat_kernel(
    const unsigned short* __restrict__ A, const unsigned short* __restrict__ Bw,
    const float* __restrict__ bias, float* __restrict__ C) {
  __shared__ __align__(16) unsigned char smem[32768];   // 2 x (A 8KB + B 8KB)

  const int tid = threadIdx.x;
  const int lane = tid & 63;
  const int wid = tid >> 6;

  const int swz = (blockIdx.x & 7) * 1024 + (blockIdx.x >> 3);
  const int st = swz >> 8;
  const int loc = swz & 255;
  const int tm = (st >> 3) * 16 + (loc & 15);
  const int tn = (st & 7) * 16 + (loc >> 4);
  const int brow = tm * 128;
  const int bcol = tn * 128;

  const int wr = wid >> 1, wc = wid & 1;

  const int ch0 = wid * 2;
  const int r0 = ch0 * 16 + (lane >> 2);
  const int kq = (lane & 3) * 8;

  f32x4 acc[4][4] = {};

#define STAGE(bufbase, t)                                                      \
  {                                                                            \
    const int k0_ = (t) * 32;                                                  \
    _Pragma("unroll")                                                          \
    for (int cc = 0; cc < 2; ++cc) {                                           \
      const int r_ = r0 + cc * 16;                                             \
      __builtin_amdgcn_global_load_lds(                                        \
          (const __attribute__((address_space(1))) void*)(const void*)         \
              (A + (size_t)(brow + r_) * LAT + k0_ + kq),                      \
          (__attribute__((address_space(3))) void*)(void*)                     \
              &smem[(bufbase) + (ch0 + cc) * 1024], 16, 0, 0);                 \
      __builtin_amdgcn_global_load_lds(                                        \
          (const __attribute__((address_space(1))) void*)(const void*)         \
              (Bw + (size_t)(bcol + r_) * LAT + k0_ + kq),                     \
          (__attribute__((address_space(3))) void*)(void*)                     \
              &smem[(bufbase) + 8192 + (ch0 + cc) * 1024], 16, 0, 0);          \
    }                                                                          \
  }

  STAGE(0, 0);
  __syncthreads();

#pragma unroll
  for (int t = 0; t < 8; ++t) {
    const int bufb = (t & 1) * 16384;
    if (t < 7) STAGE(bufb ^ 16384, t + 1);

    bf16x8 af[4], bfr[4];
#pragma unroll
    for (int mf = 0; mf < 4; ++mf)
      af[mf] = *(const bf16x8*)&smem[bufb + (wr * 64 + mf * 16 + (lane & 15)) * 64 + (lane >> 4) * 16];
#pragma unroll
    for (int nf = 0; nf < 4; ++nf)
      bfr[nf] = *(const bf16x8*)&smem[bufb + 8192 + (wc * 64 + nf * 16 + (lane & 15)) * 64 + (lane >> 4) * 16];

#pragma unroll
    for (int mf = 0; mf < 4; ++mf)
#pragma unroll
      for (int nf = 0; nf < 4; ++nf)
        acc[mf][nf] = __builtin_amdgcn_mfma_f32_16x16x32_bf16(af[mf], bfr[nf], acc[mf][nf], 0, 0, 0);

    if (t < 7) __syncthreads();
  }
#undef STAGE

  // ---- epilogue: per-wave LDS transpose -> full-line (256B-segment) nt stores ----
  __syncthreads();
  float* tt = (float*)(smem + wid * (16 * TSTRIDE * 4));

  const int colq = (lane & 15) * 4;
  const int col0 = bcol + wc * 64 + colq;
  const float4 bv4 = *(const float4*)(bias + col0);

#pragma unroll
  for (int mf = 0; mf < 4; ++mf) {
#pragma unroll
    for (int nf = 0; nf < 4; ++nf) {
      const int cl = nf * 16 + (lane & 15);
#pragma unroll
      for (int q = 0; q < 4; ++q)
        tt[((lane >> 4) * 4 + q) * TSTRIDE + cl] = acc[mf][nf][q];
    }
#pragma unroll
    for (int rr = 0; rr < 4; ++rr) {
      const int rl = rr * 4 + (lane >> 4);
      float4 v = *(const float4*)&tt[rl * TSTRIDE + colq];
      f32x4 ve;
      ve[0] = v.x + bv4.x; ve[1] = v.y + bv4.y;
      ve[2] = v.z + bv4.z; ve[3] = v.w + bv4.w;
      const int row = brow + wr * 64 + mf * 16 + rl;
      __builtin_nontemporal_store(ve, (f32x4*)&C[(size_t)row * NPIX + col0]);
    }
  }
}

extern "C" void kernel_launch(void* const* d_in, const int* in_sizes, int n_in,
                              void* d_out, int out_size, void* d_ws, size_t ws_size,
                              hipStream_t stream) {
  const float* z    = (const float*)d_in[0];
  const float* mem  = (const float*)d_in[1];
  const float* W    = (const float*)d_in[2];
  const float* bias = (const float*)d_in[3];

  float* xhat = (float*)d_out;                       // [B_DIM][NPIX]
  float* zhat = xhat + (size_t)B_DIM * NPIX;         // [B_DIM][LAT]
  float* wout = zhat + (size_t)B_DIM * LAT;          // [B_DIM][MEM_DIM]

  // Scratch in the xhat region of d_out (~13.7MB << 537MB)
  unsigned short* z_h    = (unsigned short*)xhat;
  unsigned short* z_m    = z_h + (size_t)B_DIM * LAT;
  unsigned short* z_l    = z_m + (size_t)B_DIM * LAT;
  unsigned short* mem_h  = z_l + (size_t)B_DIM * LAT;
  unsigned short* mem_m  = mem_h + (size_t)MEM_PAD * LAT;
  unsigned short* mem_l  = mem_m + (size_t)MEM_PAD * LAT;
  unsigned short* memT_h = mem_l + (size_t)MEM_PAD * LAT;
  unsigned short* memT_m = memT_h + (size_t)256 * MEMT_S;
  unsigned short* memT_l = memT_m + (size_t)256 * MEMT_S;

  // workspace: Wb 8.4MB | zhb 4.2MB | mn 800B
  unsigned short* Wb  = (unsigned short*)d_ws;
  unsigned short* zhb = Wb + (size_t)NPIX * LAT;
  float* mn = (float*)(zhb + (size_t)B_DIM * LAT);

  mem_norm_kernel<<<MEMT_K, 64, 0, stream>>>(mem, mn, mem_h, mem_m, mem_l,
                                             memT_h, memT_m, memT_l);
  prep_kernel<<<(W_QUADS + Z_QUADS) / 256, 256, 0, stream>>>(W, Wb, z, z_h, z_m, z_l);
  row_kernel<<<B_DIM / RPB, 512, 0, stream>>>(z, mn, z_h, z_m, z_l,
                                              mem_h, mem_m, mem_l,
                                              memT_h, memT_m, memT_l,
                                              zhat, wout, zhb);
  gemm_xhat_kernel<<<8192, 256, 0, stream>>>(zhb, Wb, bias, xhat);
}

// Round 19
// 202.076 us; speedup vs baseline: 1.0198x; 1.0198x over previous
//
#include <hip/hip_runtime.h>
#include <hip/hip_bf16.h>
#include <stdint.h>

// Problem dims (fixed by the reference)
#define B_DIM   8192
#define LAT     256
#define MEM_DIM 200
#define MEM_PAD 208            // padded to 13 x 16-row MFMA fragments (phase-1 B-operand)
#define MEMT_K  224            // memT k-dim padded to 7 x 32 (phase-3 contraction)
#define MEMT_S  232            // memT row stride (bf16)
#define NPIX    16384          // IMG*IMG = 128*128
#define RPB     16             // batch rows per block (r15/r17-proven)
#define W_QUADS (NPIX * LAT / 4)    // 1,048,576
#define Z_QUADS (B_DIM * LAT / 4)   //   524,288

typedef short bf16x8 __attribute__((ext_vector_type(8)));
typedef float f32x4  __attribute__((ext_vector_type(4)));

__device__ __forceinline__ float wred_sum(float v) {
#pragma unroll
  for (int m = 32; m; m >>= 1) v += __shfl_xor(v, m, 64);
  return v;
}
__device__ __forceinline__ float wred_max(float v) {
#pragma unroll
  for (int m = 32; m; m >>= 1) v = fmaxf(v, __shfl_xor(v, m, 64));
  return v;
}
// round-to-nearest-even fp32 -> bf16 (bit trick; inputs are normal floats)
__device__ __forceinline__ unsigned short f2bf(float f) {
  unsigned u = __builtin_bit_cast(unsigned, f);
  u = u + 0x7FFFu + ((u >> 16) & 1u);
  return (unsigned short)(u >> 16);
}
__device__ __forceinline__ float bf2f(unsigned short h) {
  return __builtin_bit_cast(float, (unsigned)h << 16);
}
// 3-level bf16 split: v = h + m + l + r, |r| <= 2^-27 |v|
__device__ __forceinline__ void split3(float v, unsigned short& h, unsigned short& m,
                                       unsigned short& l) {
  h = f2bf(v);
  float r1 = v - bf2f(h);
  m = f2bf(r1);
  float r2 = r1 - bf2f(m);
  l = f2bf(r2);
}

// ------- memory prep: row norms + 3-way split (rows) + 3-way split TRANSPOSE -------
__global__ void __launch_bounds__(64) mem_norm_kernel(
    const float* __restrict__ mem, float* __restrict__ mn,
    unsigned short* __restrict__ mem_h, unsigned short* __restrict__ mem_m,
    unsigned short* __restrict__ mem_l,
    unsigned short* __restrict__ memT_h, unsigned short* __restrict__ memT_m,
    unsigned short* __restrict__ memT_l) {
  const int m = blockIdx.x, lane = threadIdx.x;
  if (m >= MEM_DIM) {
    ushort4 zz = {0, 0, 0, 0};
    if (m < MEM_PAD) {
      ((ushort4*)(mem_h + (size_t)m * LAT))[lane] = zz;
      ((ushort4*)(mem_m + (size_t)m * LAT))[lane] = zz;
      ((ushort4*)(mem_l + (size_t)m * LAT))[lane] = zz;
    }
#pragma unroll
    for (int q = 0; q < 4; ++q) {
      const size_t o = (size_t)(lane * 4 + q) * MEMT_S + m;
      memT_h[o] = 0; memT_m[o] = 0; memT_l[o] = 0;
    }
    return;
  }
  float4 v = ((const float4*)(mem + (size_t)m * LAT))[lane];
  ushort4 h, md, l;
  split3(v.x, h.x, md.x, l.x); split3(v.y, h.y, md.y, l.y);
  split3(v.z, h.z, md.z, l.z); split3(v.w, h.w, md.w, l.w);
  ((ushort4*)(mem_h + (size_t)m * LAT))[lane] = h;
  ((ushort4*)(mem_m + (size_t)m * LAT))[lane] = md;
  ((ushort4*)(mem_l + (size_t)m * LAT))[lane] = l;
  const float vv[4] = {v.x, v.y, v.z, v.w};
#pragma unroll
  for (int q = 0; q < 4; ++q) {
    unsigned short th, tm, tl;
    split3(vv[q], th, tm, tl);
    const size_t o = (size_t)(lane * 4 + q) * MEMT_S + m;
    memT_h[o] = th; memT_m[o] = tm; memT_l[o] = tl;
  }
  float ss = v.x * v.x + v.y * v.y + v.z * v.z + v.w * v.w;
  ss = wred_sum(ss);
  if (lane == 0) mn[m] = sqrtf(ss);
}

// ------- fused prep: W fp32->bf16 convert + z 3-way split (one launch) -------
__global__ void __launch_bounds__(256) prep_kernel(
    const float* __restrict__ W, unsigned short* __restrict__ Wb,
    const float* __restrict__ z, unsigned short* __restrict__ z_h,
    unsigned short* __restrict__ z_m, unsigned short* __restrict__ z_l) {
  const int i = blockIdx.x * 256 + threadIdx.x;
  if (i < W_QUADS) {
    float4 v = ((const float4*)W)[i];
    ushort4 o;
    o.x = f2bf(v.x); o.y = f2bf(v.y); o.z = f2bf(v.z); o.w = f2bf(v.w);
    ((ushort4*)Wb)[i] = o;
  } else {
    const int j = i - W_QUADS;
    float4 v = ((const float4*)z)[j];
    ushort4 h, md, l;
    split3(v.x, h.x, md.x, l.x); split3(v.y, h.y, md.y, l.y);
    split3(v.z, h.z, md.z, l.z); split3(v.w, h.w, md.w, l.w);
    ((ushort4*)z_h)[j] = h;
    ((ushort4*)z_m)[j] = md;
    ((ushort4*)z_l)[j] = l;
  }
}

// ---------------- fused per-row pipeline (r15/r17 version, 256 threads, UNCHANGED) ----------------
__global__ void __launch_bounds__(256) row_kernel(
    const float* __restrict__ z, const float* __restrict__ mn_g,
    const unsigned short* __restrict__ z_h, const unsigned short* __restrict__ z_m,
    const unsigned short* __restrict__ z_l,
    const unsigned short* __restrict__ mem_h, const unsigned short* __restrict__ mem_m,
    const unsigned short* __restrict__ mem_l,
    const unsigned short* __restrict__ memT_h, const unsigned short* __restrict__ memT_m,
    const unsigned short* __restrict__ memT_l,
    float* __restrict__ zhat_out, float* __restrict__ w_out,
    unsigned short* __restrict__ zhat_bf) {
  __shared__ float lw[RPB][MEM_DIM];              // 12.8 KB: logits, then final w
  __shared__ float mnsh[MEM_DIM];
  __shared__ unsigned short whsh[16 * MEMT_S];    // 7.25 KB x3: w splits
  __shared__ unsigned short wmsh[16 * MEMT_S];
  __shared__ unsigned short wlsh[16 * MEMT_S];

  const int tid = threadIdx.x;
  const int lane = tid & 63;
  const int wid = tid >> 6;
  const int row0 = blockIdx.x * RPB;
  const int fr_ = lane & 15;
  const int kq8 = (lane >> 4) * 8;

  if (tid < MEM_DIM) mnsh[tid] = mn_g[tid];

  float zn[4];
#pragma unroll
  for (int r = 0; r < 4; ++r) {
    const int row = row0 + wid * 4 + r;
    float4 zr = *(const float4*)(z + (size_t)row * LAT + lane * 4);
    float ss = zr.x * zr.x + zr.y * zr.y + zr.z * zr.z + zr.w * zr.w;
    zn[r] = sqrtf(wred_sum(ss));
  }

  // ---- phase 1: logits via 6-term split MFMA ----
  {
    const size_t zoff = (size_t)(row0 + fr_) * LAT + kq8;
    const unsigned short* zh_p = z_h + zoff;
    const unsigned short* zm_p = z_m + zoff;
    const unsigned short* zl_p = z_l + zoff;
    for (int nf = wid; nf <= 12; nf += 4) {
      const size_t moff = (size_t)(nf * 16 + fr_) * LAT + kq8;
      const unsigned short* mh_p = mem_h + moff;
      const unsigned short* mm_p = mem_m + moff;
      const unsigned short* ml_p = mem_l + moff;
      f32x4 a = {};
#pragma unroll
      for (int kk = 0; kk < 8; ++kk) {
        bf16x8 zh = *(const bf16x8*)(zh_p + kk * 32);
        bf16x8 zm = *(const bf16x8*)(zm_p + kk * 32);
        bf16x8 zl = *(const bf16x8*)(zl_p + kk * 32);
        bf16x8 mh = *(const bf16x8*)(mh_p + kk * 32);
        bf16x8 mm = *(const bf16x8*)(mm_p + kk * 32);
        bf16x8 ml = *(const bf16x8*)(ml_p + kk * 32);
        a = __builtin_amdgcn_mfma_f32_16x16x32_bf16(zm, mm, a, 0, 0, 0);
        a = __builtin_amdgcn_mfma_f32_16x16x32_bf16(zh, ml, a, 0, 0, 0);
        a = __builtin_amdgcn_mfma_f32_16x16x32_bf16(zl, mh, a, 0, 0, 0);
        a = __builtin_amdgcn_mfma_f32_16x16x32_bf16(zm, mh, a, 0, 0, 0);
        a = __builtin_amdgcn_mfma_f32_16x16x32_bf16(zh, mm, a, 0, 0, 0);
        a = __builtin_amdgcn_mfma_f32_16x16x32_bf16(zh, mh, a, 0, 0, 0);
      }
      const int m = nf * 16 + fr_;
      if (m < MEM_DIM) {
#pragma unroll
        for (int q = 0; q < 4; ++q)
          lw[(lane >> 4) * 4 + q][m] = a[q];
      }
    }
  }
  __syncthreads();

  // ---- phase 2: cosine scale -> softmax -> shrink -> L1 normalize ----
  const float t = 0.005f;
#pragma unroll
  for (int r = 0; r < 4; ++r) {
    const int lr = wid * 4 + r;
    float lg[4];
#pragma unroll
    for (int i = 0; i < 4; ++i) {
      const int m = lane + 64 * i;
      lg[i] = (m < MEM_DIM) ? lw[lr][m] / fmaxf(zn[r] * mnsh[m], 1e-8f) : -1e30f;
    }
    float mx = wred_max(fmaxf(fmaxf(lg[0], lg[1]), fmaxf(lg[2], lg[3])));
    float e[4]; float s = 0.f;
#pragma unroll
    for (int i = 0; i < 4; ++i) {
      const int m = lane + 64 * i;
      e[i] = (m < MEM_DIM) ? expf(lg[i] - mx) : 0.f;
      s += e[i];
    }
    s = wred_sum(s);
    float sv[4]; float l1 = 0.f;
#pragma unroll
    for (int i = 0; i < 4; ++i) {
      const float wv = e[i] / s;
      const float d = wv - t;
      sv[i] = fmaxf(d, 0.f) * wv / (fabsf(d) + 1e-12f);
      l1 += sv[i];
    }
    l1 = wred_sum(l1);
    const float dnm = fmaxf(l1, 1e-12f);
#pragma unroll
    for (int i = 0; i < 4; ++i) {
      const int m = lane + 64 * i;
      if (m < MEM_DIM) {
        const float wn = sv[i] / dnm;
        lw[lr][m] = wn;
        w_out[(size_t)(row0 + lr) * MEM_DIM + m] = wn;
      }
    }
  }
  __syncthreads();

  // ---- phase 2.5: split w -> bf16 h/m/l fragment arrays in LDS ----
  for (int idx = tid; idx < 16 * MEMT_S; idx += 256) {
    const int lr = idx / MEMT_S, m = idx % MEMT_S;
    const float val = (m < MEM_DIM) ? lw[lr][m] : 0.f;
    unsigned short h, md, l;
    split3(val, h, md, l);
    whsh[idx] = h; wmsh[idx] = md; wlsh[idx] = l;
  }
  __syncthreads();

  // ---- phase 3: z_hat = w @ mem via 6-term split MFMA ----
  {
    f32x4 zacc[4] = {};
    for (int kk = 0; kk < 7; ++kk) {
      const int ko = kk * 32 + kq8;
      bf16x8 wh = *(const bf16x8*)&whsh[fr_ * MEMT_S + ko];
      bf16x8 wm = *(const bf16x8*)&wmsh[fr_ * MEMT_S + ko];
      bf16x8 wl = *(const bf16x8*)&wlsh[fr_ * MEMT_S + ko];
#pragma unroll
      for (int nf = 0; nf < 4; ++nf) {
        const size_t mo = (size_t)(wid * 64 + nf * 16 + fr_) * MEMT_S + ko;
        bf16x8 th = *(const bf16x8*)(memT_h + mo);
        bf16x8 tm = *(const bf16x8*)(memT_m + mo);
        bf16x8 tl = *(const bf16x8*)(memT_l + mo);
        zacc[nf] = __builtin_amdgcn_mfma_f32_16x16x32_bf16(tm, wm, zacc[nf], 0, 0, 0);
        zacc[nf] = __builtin_amdgcn_mfma_f32_16x16x32_bf16(th, wl, zacc[nf], 0, 0, 0);
        zacc[nf] = __builtin_amdgcn_mfma_f32_16x16x32_bf16(tl, wh, zacc[nf], 0, 0, 0);
        zacc[nf] = __builtin_amdgcn_mfma_f32_16x16x32_bf16(tm, wh, zacc[nf], 0, 0, 0);
        zacc[nf] = __builtin_amdgcn_mfma_f32_16x16x32_bf16(th, wm, zacc[nf], 0, 0, 0);
        zacc[nf] = __builtin_amdgcn_mfma_f32_16x16x32_bf16(th, wh, zacc[nf], 0, 0, 0);
      }
    }
    const size_t orow = (size_t)(row0 + fr_) * LAT;
#pragma unroll
    for (int nf = 0; nf < 4; ++nf) {
      const int d0 = wid * 64 + nf * 16 + (lane >> 4) * 4;
      float4 o;
      o.x = zacc[nf][0]; o.y = zacc[nf][1]; o.z = zacc[nf][2]; o.w = zacc[nf][3];
      *(float4*)(zhat_out + orow + d0) = o;
      ushort4 ob;
      ob.x = f2bf(o.x); ob.y = f2bf(o.y); ob.z = f2bf(o.z); ob.w = f2bf(o.w);
      *(ushort4*)(zhat_bf + orow + d0) = ob;
    }
  }
}

// ---------------- x_hat = zhat_bf @ Wb^T + bias (r17 version, UNCHANGED) ----------------
#define TSTRIDE 68
__global__ void __launch_bounds__(256, 4) gemm_xhat_kernel(
    const unsigned short* __restrict__ A, const unsigned short* __restrict__ Bw,
    const float* __restrict__ bias, float* __restrict__ C) {
  __shared__ __align__(16) unsigned char smem[32768];   // 2 x (A 8KB + B 8KB)

  const int tid = threadIdx.x;
  const int lane = tid & 63;
  const int wid = tid >> 6;

  const int swz = (blockIdx.x & 7) * 1024 + (blockIdx.x >> 3);
  const int st = swz >> 8;
  const int loc = swz & 255;
  const int tm = (st >> 3) * 16 + (loc & 15);
  const int tn = (st & 7) * 16 + (loc >> 4);
  const int brow = tm * 128;
  const int bcol = tn * 128;

  const int wr = wid >> 1, wc = wid & 1;

  const int ch0 = wid * 2;
  const int r0 = ch0 * 16 + (lane >> 2);
  const int kq = (lane & 3) * 8;

  f32x4 acc[4][4] = {};

#define STAGE(bufbase, t)                                                      \
  {                                                                            \
    const int k0_ = (t) * 32;                                                  \
    _Pragma("unroll")                                                          \
    for (int cc = 0; cc < 2; ++cc) {                                           \
      const int r_ = r0 + cc * 16;                                             \
      __builtin_amdgcn_global_load_lds(                                        \
          (const __attribute__((address_space(1))) void*)(const void*)         \
              (A + (size_t)(brow + r_) * LAT + k0_ + kq),                      \
          (__attribute__((address_space(3))) void*)(void*)                     \
              &smem[(bufbase) + (ch0 + cc) * 1024], 16, 0, 0);                 \
      __builtin_amdgcn_global_load_lds(                                        \
          (const __attribute__((address_space(1))) void*)(const void*)         \
              (Bw + (size_t)(bcol + r_) * LAT + k0_ + kq),                     \
          (__attribute__((address_space(3))) void*)(void*)                     \
              &smem[(bufbase) + 8192 + (ch0 + cc) * 1024], 16, 0, 0);          \
    }                                                                          \
  }

  STAGE(0, 0);
  __syncthreads();

#pragma unroll
  for (int t = 0; t < 8; ++t) {
    const int bufb = (t & 1) * 16384;
    if (t < 7) STAGE(bufb ^ 16384, t + 1);

    bf16x8 af[4], bfr[4];
#pragma unroll
    for (int mf = 0; mf < 4; ++mf)
      af[mf] = *(const bf16x8*)&smem[bufb + (wr * 64 + mf * 16 + (lane & 15)) * 64 + (lane >> 4) * 16];
#pragma unroll
    for (int nf = 0; nf < 4; ++nf)
      bfr[nf] = *(const bf16x8*)&smem[bufb + 8192 + (wc * 64 + nf * 16 + (lane & 15)) * 64 + (lane >> 4) * 16];

#pragma unroll
    for (int mf = 0; mf < 4; ++mf)
#pragma unroll
      for (int nf = 0; nf < 4; ++nf)
        acc[mf][nf] = __builtin_amdgcn_mfma_f32_16x16x32_bf16(af[mf], bfr[nf], acc[mf][nf], 0, 0, 0);

    if (t < 7) __syncthreads();
  }
#undef STAGE

  // ---- epilogue: per-wave LDS transpose -> full-line (256B-segment) nt stores ----
  __syncthreads();
  float* tt = (float*)(smem + wid * (16 * TSTRIDE * 4));

  const int colq = (lane & 15) * 4;
  const int col0 = bcol + wc * 64 + colq;
  const float4 bv4 = *(const float4*)(bias + col0);

#pragma unroll
  for (int mf = 0; mf < 4; ++mf) {
#pragma unroll
    for (int nf = 0; nf < 4; ++nf) {
      const int cl = nf * 16 + (lane & 15);
#pragma unroll
      for (int q = 0; q < 4; ++q)
        tt[((lane >> 4) * 4 + q) * TSTRIDE + cl] = acc[mf][nf][q];
    }
#pragma unroll
    for (int rr = 0; rr < 4; ++rr) {
      const int rl = rr * 4 + (lane >> 4);
      float4 v = *(const float4*)&tt[rl * TSTRIDE + colq];
      f32x4 ve;
      ve[0] = v.x + bv4.x; ve[1] = v.y + bv4.y;
      ve[2] = v.z + bv4.z; ve[3] = v.w + bv4.w;
      const int row = brow + wr * 64 + mf * 16 + rl;
      __builtin_nontemporal_store(ve, (f32x4*)&C[(size_t)row * NPIX + col0]);
    }
  }
}

extern "C" void kernel_launch(void* const* d_in, const int* in_sizes, int n_in,
                              void* d_out, int out_size, void* d_ws, size_t ws_size,
                              hipStream_t stream) {
  const float* z    = (const float*)d_in[0];
  const float* mem  = (const float*)d_in[1];
  const float* W    = (const float*)d_in[2];
  const float* bias = (const float*)d_in[3];

  float* xhat = (float*)d_out;                       // [B_DIM][NPIX]
  float* zhat = xhat + (size_t)B_DIM * NPIX;         // [B_DIM][LAT]
  float* wout = zhat + (size_t)B_DIM * LAT;          // [B_DIM][MEM_DIM]

  // Scratch in the xhat region of d_out (~13.7MB << 537MB)
  unsigned short* z_h    = (unsigned short*)xhat;
  unsigned short* z_m    = z_h + (size_t)B_DIM * LAT;
  unsigned short* z_l    = z_m + (size_t)B_DIM * LAT;
  unsigned short* mem_h  = z_l + (size_t)B_DIM * LAT;
  unsigned short* mem_m  = mem_h + (size_t)MEM_PAD * LAT;
  unsigned short* mem_l  = mem_m + (size_t)MEM_PAD * LAT;
  unsigned short* memT_h = mem_l + (size_t)MEM_PAD * LAT;
  unsigned short* memT_m = memT_h + (size_t)256 * MEMT_S;
  unsigned short* memT_l = memT_m + (size_t)256 * MEMT_S;

  // workspace: Wb 8.4MB | zhb 4.2MB | mn 800B
  unsigned short* Wb  = (unsigned short*)d_ws;
  unsigned short* zhb = Wb + (size_t)NPIX * LAT;
  float* mn = (float*)(zhb + (size_t)B_DIM * LAT);

  mem_norm_kernel<<<MEMT_K, 64, 0, stream>>>(mem, mn, mem_h, mem_m, mem_l,
                                             memT_h, memT_m, memT_l);
  prep_kernel<<<(W_QUADS + Z_QUADS) / 256, 256, 0, stream>>>(W, Wb, z, z_h, z_m, z_l);
  row_kernel<<<B_DIM / RPB, 256, 0, stream>>>(z, mn, z_h, z_m, z_l,
                                              mem_h, mem_m, mem_l,
                                              memT_h, memT_m, memT_l,
                                              zhat, wout, zhb);
  gemm_xhat_kernel<<<8192, 256, 0, stream>>>(zhb, Wb, bias, xhat);
}